// Round 1
// baseline (193.945 us; speedup 1.0000x reference)
//
#include <hip/hip_runtime.h>
#include <math.h>

#define FFT_N   4096
#define LOG2N   12
#define THREADS 256
#define STAGES  6                       // radix-4: 4^6 = 4096
#define BPT     (FFT_N / 4 / THREADS)   // butterflies per thread per stage = 4

__device__ __forceinline__ int pad(int i) { return i + (i >> 5); }

// Gperm[p] = ((W[k] + W[(N-k)%N])/2 + 1) / N  at  k = base4_digit_reverse(p)
__global__ void setup_g_kernel(const float* __restrict__ fw, float* __restrict__ gperm) {
    int p = blockIdx.x * blockDim.x + threadIdx.x;
    if (p >= FFT_N) return;
    unsigned b = __brev((unsigned)p) >> (32 - LOG2N);            // 12-bit bit reversal
    unsigned k = ((b & 0x555u) << 1) | ((b & 0xAAAu) >> 1);      // -> base-4 digit reversal
    float wk  = fw[k];
    float wnk = fw[(FFT_N - k) & (FFT_N - 1)];
    gperm[p] = (0.5f * (wk + wnk) + 1.0f) * (1.0f / (float)FFT_N);
}

__global__ __launch_bounds__(THREADS) void fourier_fft_kernel(
    const float* __restrict__ in, const float* __restrict__ gperm,
    const float* __restrict__ lw, float* __restrict__ out)
{
    __shared__ float re[FFT_N + (FFT_N >> 5)];
    __shared__ float im[FFT_N + (FFT_N >> 5)];

    const int tid = threadIdx.x;
    const long long pair = blockIdx.x;
    const float* r0 = in + pair * (2LL * FFT_N);
    const float* r1 = r0 + FFT_N;

    // load two rows as one complex signal z = x1 + i*x2
    #pragma unroll
    for (int q = 0; q < FFT_N / THREADS; ++q) {
        int i = tid + q * THREADS;
        re[pad(i)] = r0[i];
        im[pad(i)] = r1[i];
    }
    // no barrier: forward stage 0 reads exactly this thread's own writes

    const float CF = -6.28318530717958647692f / (float)FFT_N;

    // ---------------- forward DIF radix-4 (natural in -> digit-reversed out)
    for (int s = 0; s < STAGES; ++s) {
        if (s > 0) __syncthreads();
        const int log2L = LOG2N - 2 * s;
        const int log2M = log2L - 2;
        const int M = 1 << log2M;
        const int step = 1 << (2 * s);          // N / L
        #pragma unroll
        for (int q = 0; q < BPT; ++q) {
            const int m = tid + q * THREADS;
            const int j = m & (M - 1);
            const int g = m >> log2M;
            const int base = (g << log2L) + j;
            const int i0 = pad(base), i1 = pad(base + M), i2 = pad(base + 2 * M), i3 = pad(base + 3 * M);
            float ar = re[i0], ai = im[i0];
            float br = re[i1], bi = im[i1];
            float cr = re[i2], ci = im[i2];
            float dr = re[i3], di = im[i3];
            float t0r = ar + cr, t0i = ai + ci;
            float t1r = ar - cr, t1i = ai - ci;
            float t2r = br + dr, t2i = bi + di;
            float t3r = br - dr, t3i = bi - di;
            float th = CF * (float)(j * step);
            float s1, c1;
            __sincosf(th, &s1, &c1);
            float c2 = c1 * c1 - s1 * s1, s2 = 2.0f * c1 * s1;   // w^2
            float c3 = c1 * c2 - s1 * s2, s3 = c1 * s2 + s1 * c2; // w^3
            float Ar = t0r + t2r, Ai = t0i + t2i;                 // t0 + t2
            float Br = t1r + t3i, Bi = t1i - t3r;                 // t1 - i*t3
            float Cr = t0r - t2r, Ci = t0i - t2i;                 // t0 - t2
            float Dr = t1r - t3i, Di = t1i + t3r;                 // t1 + i*t3
            re[i0] = Ar;                 im[i0] = Ai;
            re[i1] = Br * c1 - Bi * s1;  im[i1] = Br * s1 + Bi * c1;
            re[i2] = Cr * c2 - Ci * s2;  im[i2] = Cr * s2 + Ci * c2;
            re[i3] = Dr * c3 - Di * s3;  im[i3] = Dr * s3 + Di * c3;
        }
    }

    // ---------------- inverse DIT radix-4 stage 0: twiddles == 1, fuse G multiply.
    // Same thread wrote these 4 slots in forward stage 5 -> no barrier needed.
    #pragma unroll
    for (int q = 0; q < BPT; ++q) {
        const int m = tid + q * THREADS;
        const int base = 4 * m;
        const int i0 = pad(base), i1 = pad(base + 1), i2 = pad(base + 2), i3 = pad(base + 3);
        float g0 = gperm[base], g1 = gperm[base + 1], g2 = gperm[base + 2], g3 = gperm[base + 3];
        float Ar = re[i0] * g0, Ai = im[i0] * g0;
        float Br = re[i1] * g1, Bi = im[i1] * g1;
        float Cr = re[i2] * g2, Ci = im[i2] * g2;
        float Dr = re[i3] * g3, Di = im[i3] * g3;
        float s0r = Ar + Cr, s0i = Ai + Ci;
        float s1r = Ar - Cr, s1i = Ai - Ci;
        float s2r = Br + Dr, s2i = Bi + Di;
        float s3r = Di - Bi, s3i = Br - Dr;     // i*(B - D)
        re[i0] = s0r + s2r; im[i0] = s0i + s2i;
        re[i1] = s1r + s3r; im[i1] = s1i + s3i;
        re[i2] = s0r - s2r; im[i2] = s0i - s2i;
        re[i3] = s1r - s3r; im[i3] = s1i - s3i;
    }

    // ---------------- inverse DIT radix-4 stages 1..5 (digit-reversed -> natural)
    for (int s = 1; s < STAGES; ++s) {
        __syncthreads();
        const int log2L = 2 + 2 * s;
        const int log2M = log2L - 2;
        const int M = 1 << log2M;
        const int step = 1 << (LOG2N - log2L);
        #pragma unroll
        for (int q = 0; q < BPT; ++q) {
            const int m = tid + q * THREADS;
            const int j = m & (M - 1);
            const int g = m >> log2M;
            const int base = (g << log2L) + j;
            const int i0 = pad(base), i1 = pad(base + M), i2 = pad(base + 2 * M), i3 = pad(base + 3 * M);
            float th = -CF * (float)(j * step);   // conjugate twiddles
            float s1, c1;
            __sincosf(th, &s1, &c1);
            float c2 = c1 * c1 - s1 * s1, s2 = 2.0f * c1 * s1;
            float c3 = c1 * c2 - s1 * s2, s3 = c1 * s2 + s1 * c2;
            float Ar = re[i0], Ai = im[i0];
            float br0 = re[i1], bi0 = im[i1];
            float cr0 = re[i2], ci0 = im[i2];
            float dr0 = re[i3], di0 = im[i3];
            float Br = br0 * c1 - bi0 * s1, Bi = br0 * s1 + bi0 * c1;
            float Cr = cr0 * c2 - ci0 * s2, Ci = cr0 * s2 + ci0 * c2;
            float Dr = dr0 * c3 - di0 * s3, Di = dr0 * s3 + di0 * c3;
            float s0r = Ar + Cr, s0i = Ai + Ci;
            float s1r_ = Ar - Cr, s1i_ = Ai - Ci;
            float s2r = Br + Dr, s2i = Bi + Di;
            float s3r = Di - Bi, s3i = Br - Dr;   // i*(B - D)
            re[i0] = s0r + s2r;  im[i0] = s0i + s2i;
            re[i1] = s1r_ + s3r; im[i1] = s1i_ + s3i;
            re[i2] = s0r - s2r;  im[i2] = s0i - s2i;
            re[i3] = s1r_ - s3r; im[i3] = s1i_ - s3i;
        }
    }

    // ---------------- epilogue: y(+skip already folded) * lw, relu.
    // Last inverse stage wrote exactly this thread's positions -> no barrier.
    float* o0 = out + pair * (2LL * FFT_N);
    #pragma unroll
    for (int q = 0; q < FFT_N / THREADS; ++q) {
        int i = tid + q * THREADS;
        float l = lw[i];
        float y0 = re[pad(i)] * l;
        float y1 = im[pad(i)] * l;
        o0[i]         = fmaxf(y0, 0.0f);
        o0[FFT_N + i] = fmaxf(y1, 0.0f);
    }
}

extern "C" void kernel_launch(void* const* d_in, const int* in_sizes, int n_in,
                              void* d_out, int out_size, void* d_ws, size_t ws_size,
                              hipStream_t stream) {
    const float* inputs = (const float*)d_in[0];
    const float* fw     = (const float*)d_in[1];
    const float* lw     = (const float*)d_in[2];
    float* out   = (float*)d_out;
    float* gperm = (float*)d_ws;   // 4096 floats = 16 KB scratch

    hipLaunchKernelGGL(setup_g_kernel, dim3(FFT_N / THREADS), dim3(THREADS), 0, stream,
                       fw, gperm);

    const int pairs = in_sizes[0] / (2 * FFT_N);   // 16384 rows -> 8192 pairs
    hipLaunchKernelGGL(fourier_fft_kernel, dim3(pairs), dim3(THREADS), 0, stream,
                       inputs, gperm, lw, out);
}

// Round 2
// 119.772 us; speedup vs baseline: 1.6193x; 1.6193x over previous
//
#include <hip/hip_runtime.h>
#include <math.h>

#define FFT_N   4096
#define THREADS 256
#define PADN    (FFT_N + (FFT_N >> 5))

// Gperm[p] = ((W[k] + W[(N-k)%N])/2 + 1) / N  at  k = base16_digit_reverse(p)
__global__ void setup_g_kernel(const float* __restrict__ fw, float* __restrict__ gperm) {
    int p = blockIdx.x * blockDim.x + threadIdx.x;
    if (p >= FFT_N) return;
    unsigned k = ((p & 15u) << 8) | (p & 0xF0u) | ((unsigned)p >> 8);  // 3-digit base-16 reversal
    float wk  = fw[k];
    float wnk = fw[(FFT_N - k) & (FFT_N - 1)];
    gperm[p] = (0.5f * (wk + wnk) + 1.0f) * (1.0f / (float)FFT_N);
}

// in-register 16-point DFT, natural-order in/out.
// DIR=+1: W=e^{-2pi i/16} (forward). DIR=-1: unnormalized inverse.
template<int DIR>
__device__ __forceinline__ void dft16(float xr[16], float xi[16]) {
    const float C1 = 0.9238795325112867f;   // cos(pi/8)
    const float S1 = 0.3826834323650898f;   // sin(pi/8)
    const float H  = 0.7071067811865476f;
    // cos/sin(pi*e/8), e=0..9
    const float TCt[10] = {1.f, C1, H, S1, 0.f, -S1, -H, -C1, -1.f, -C1};
    const float TSt[10] = {0.f, S1, H, C1, 1.f,  C1, H,  S1,  0.f, -S1};
    float tr[16], ti[16];
    #pragma unroll
    for (int m0 = 0; m0 < 4; ++m0) {
        float ar = xr[m0+ 0], ai = xi[m0+ 0];
        float br = xr[m0+ 4], bi = xi[m0+ 4];
        float cr = xr[m0+ 8], ci = xi[m0+ 8];
        float dr = xr[m0+12], di = xi[m0+12];
        float t0r = ar+cr, t0i = ai+ci;
        float t1r = ar-cr, t1i = ai-ci;
        float t2r = br+dr, t2i = bi+di;
        float t3r = br-dr, t3i = bi-di;
        float A0r = t0r+t2r, A0i = t0i+t2i;
        float A2r = t0r-t2r, A2i = t0i-t2i;
        float A1r, A1i, A3r, A3i;
        if (DIR > 0) { A1r = t1r + t3i; A1i = t1i - t3r; A3r = t1r - t3i; A3i = t1i + t3r; }
        else         { A1r = t1r - t3i; A1i = t1i + t3r; A3r = t1r + t3i; A3i = t1i - t3r; }
        // twiddle W16^{±m0*k0}; store at t[k0*4 + m0]
        tr[0*4+m0] = A0r; ti[0*4+m0] = A0i;
        {   // k0=1, e=m0
            float c = TCt[m0], s = (DIR > 0) ? -TSt[m0] : TSt[m0];
            float vr = A1r*c - A1i*s, vi = A1r*s + A1i*c;
            tr[1*4+m0] = vr; ti[1*4+m0] = vi;
        }
        {   // k0=2, e=2*m0
            float c = TCt[2*m0], s = (DIR > 0) ? -TSt[2*m0] : TSt[2*m0];
            float vr = A2r*c - A2i*s, vi = A2r*s + A2i*c;
            tr[2*4+m0] = vr; ti[2*4+m0] = vi;
        }
        {   // k0=3, e=3*m0
            float c = TCt[3*m0], s = (DIR > 0) ? -TSt[3*m0] : TSt[3*m0];
            float vr = A3r*c - A3i*s, vi = A3r*s + A3i*c;
            tr[3*4+m0] = vr; ti[3*4+m0] = vi;
        }
    }
    #pragma unroll
    for (int k0 = 0; k0 < 4; ++k0) {
        float ar = tr[k0*4+0], ai = ti[k0*4+0];
        float br = tr[k0*4+1], bi = ti[k0*4+1];
        float cr = tr[k0*4+2], ci = ti[k0*4+2];
        float dr = tr[k0*4+3], di = ti[k0*4+3];
        float t0r = ar+cr, t0i = ai+ci;
        float t1r = ar-cr, t1i = ai-ci;
        float t2r = br+dr, t2i = bi+di;
        float t3r = br-dr, t3i = bi-di;
        xr[k0+ 0] = t0r+t2r; xi[k0+ 0] = t0i+t2i;
        xr[k0+ 8] = t0r-t2r; xi[k0+ 8] = t0i-t2i;
        if (DIR > 0) {
            xr[k0+ 4] = t1r + t3i; xi[k0+ 4] = t1i - t3r;
            xr[k0+12] = t1r - t3i; xi[k0+12] = t1i + t3r;
        } else {
            xr[k0+ 4] = t1r - t3i; xi[k0+ 4] = t1i + t3r;
            xr[k0+12] = t1r + t3i; xi[k0+12] = t1i - t3r;
        }
    }
}

// multiply xr[k]+i*xi[k] by w^k, w = (cos ang1, sin ang1), via product chain
__device__ __forceinline__ void twiddle_apply(float xr[16], float xi[16], float ang1) {
    float s1, c1;
    __sincosf(ang1, &s1, &c1);
    float wc = c1, ws = s1;
    #pragma unroll
    for (int k = 1; k < 16; ++k) {
        float tv = xr[k];
        xr[k] = tv*wc - xi[k]*ws;
        xi[k] = tv*ws + xi[k]*wc;
        if (k < 15) { float nc = wc*c1 - ws*s1; ws = wc*s1 + ws*c1; wc = nc; }
    }
}

__global__ __launch_bounds__(THREADS, 4) void fourier_fft_kernel(
    const float* __restrict__ in, const float* __restrict__ gperm,
    const float* __restrict__ lw, float* __restrict__ out)
{
    __shared__ float re[PADN];
    __shared__ float im[PADN];
    const int t = threadIdx.x;
    const long long pair = blockIdx.x;
    const float* r0 = in + pair * (2LL * FFT_N);
    const float* r1 = r0 + FFT_N;

    const float CFA = -6.28318530717958647692f / 4096.0f;
    const float CFB = -6.28318530717958647692f / 256.0f;

    float xr[16], xi[16];

    // load: thread t owns x[t + 256k] — coalesced
    #pragma unroll
    for (int k = 0; k < 16; ++k) {
        xr[k] = r0[t + 256*k];
        xi[k] = r1[t + 256*k];
    }

    // ---- forward stage A (L=4096, j=t): DFT16, twiddle W4096^{t*k}
    dft16<1>(xr, xi);
    twiddle_apply(xr, xi, CFA * (float)t);
    #pragma unroll
    for (int k = 0; k < 16; ++k) { int s = t + 256*k; s += s>>5; re[s] = xr[k]; im[s] = xi[k]; }
    __syncthreads();

    // ---- forward stage B (L=256, j=t&15)
    const int jb = t & 15;
    const int baseB = (t >> 4)*256 + jb;
    #pragma unroll
    for (int k = 0; k < 16; ++k) { int s = baseB + 16*k; s += s>>5; xr[k] = re[s]; xi[k] = im[s]; }
    dft16<1>(xr, xi);
    twiddle_apply(xr, xi, CFB * (float)jb);
    #pragma unroll
    for (int k = 0; k < 16; ++k) { int s = baseB + 16*k; s += s>>5; re[s] = xr[k]; im[s] = xi[k]; }
    __syncthreads();

    // ---- forward stage C (L=16, unit twiddles) + pointwise G + inverse stage C'
    //      all in registers; C' writes exactly the slots C read -> no barrier inside
    #pragma unroll
    for (int k = 0; k < 16; ++k) { int s = 16*t + k; s += s>>5; xr[k] = re[s]; xi[k] = im[s]; }
    dft16<1>(xr, xi);
    {
        const float4* gp = (const float4*)(gperm + 16*t);
        #pragma unroll
        for (int q = 0; q < 4; ++q) {
            float4 g = gp[q];
            xr[4*q+0] *= g.x; xi[4*q+0] *= g.x;
            xr[4*q+1] *= g.y; xi[4*q+1] *= g.y;
            xr[4*q+2] *= g.z; xi[4*q+2] *= g.z;
            xr[4*q+3] *= g.w; xi[4*q+3] *= g.w;
        }
    }
    dft16<-1>(xr, xi);
    #pragma unroll
    for (int k = 0; k < 16; ++k) { int s = 16*t + k; s += s>>5; re[s] = xr[k]; im[s] = xi[k]; }
    __syncthreads();

    // ---- inverse stage B' (L=256): conj twiddle on inputs, then IDFT16
    #pragma unroll
    for (int k = 0; k < 16; ++k) { int s = baseB + 16*k; s += s>>5; xr[k] = re[s]; xi[k] = im[s]; }
    twiddle_apply(xr, xi, -CFB * (float)jb);
    dft16<-1>(xr, xi);
    #pragma unroll
    for (int k = 0; k < 16; ++k) { int s = baseB + 16*k; s += s>>5; re[s] = xr[k]; im[s] = xi[k]; }
    __syncthreads();

    // ---- inverse stage A' (L=4096) + epilogue, straight from registers
    #pragma unroll
    for (int k = 0; k < 16; ++k) { int s = t + 256*k; s += s>>5; xr[k] = re[s]; xi[k] = im[s]; }
    twiddle_apply(xr, xi, -CFA * (float)t);
    dft16<-1>(xr, xi);

    float* o0 = out + pair * (2LL * FFT_N);
    #pragma unroll
    for (int k = 0; k < 16; ++k) {
        int i = t + 256*k;
        float l = lw[i];
        o0[i]         = fmaxf(xr[k]*l, 0.0f);
        o0[FFT_N + i] = fmaxf(xi[k]*l, 0.0f);
    }
}

extern "C" void kernel_launch(void* const* d_in, const int* in_sizes, int n_in,
                              void* d_out, int out_size, void* d_ws, size_t ws_size,
                              hipStream_t stream) {
    const float* inputs = (const float*)d_in[0];
    const float* fw     = (const float*)d_in[1];
    const float* lw     = (const float*)d_in[2];
    float* out   = (float*)d_out;
    float* gperm = (float*)d_ws;   // 4096 floats = 16 KB scratch

    hipLaunchKernelGGL(setup_g_kernel, dim3(FFT_N / THREADS), dim3(THREADS), 0, stream,
                       fw, gperm);

    const int pairs = in_sizes[0] / (2 * FFT_N);   // 16384 rows -> 8192 pairs
    hipLaunchKernelGGL(fourier_fft_kernel, dim3(pairs), dim3(THREADS), 0, stream,
                       inputs, gperm, lw, out);
}